// Round 1
// baseline (572.890 us; speedup 1.0000x reference)
//
#include <hip/hip_runtime.h>
#include <math.h>

#define NB 8
#define NC 64
#define NHEADS 4
#define NTOK 65536

// workspace layout (floats)
constexpr int CS_OFF = 0;        // float2 [256][32]  -> 16384 floats
constexpr int KV_OFF = 16384;    // [8][4][16][16]    -> 8192 floats
constexpr int KM_OFF = 24576;    // [8][64]           -> 512 floats

__global__ __launch_bounds__(256) void k0_setup(float* __restrict__ ws) {
    int i = blockIdx.x * 256 + threadIdx.x;
    if (i < 8192) {
        int w = i >> 5, p = i & 31;
        double th = pow(10000.0, -(double)p / 32.0);
        double ang = (double)w * th;
        ws[CS_OFF + 2 * i]     = (float)cos(ang);
        ws[CS_OFF + 2 * i + 1] = (float)sin(ang);
        ws[KV_OFF + i] = 0.0f;
        if (i < 512) ws[KM_OFF + i] = 0.0f;
    }
}

// K1: per (b, ch): depthwise-conv k-columns + elu + rope, accumulate kv and k_mean
__global__ __launch_bounds__(256) void k1_kv(const float* __restrict__ x,
        const float* __restrict__ qkw, const float* __restrict__ qkb,
        float* __restrict__ ws) {
    const int b  = blockIdx.x >> 6;
    const int ch = blockIdx.x & 63;
    const int t  = threadIdx.x;
    const float* xb     = x + (size_t)b * (NC * NTOK);
    const float* xplane = xb + ch * NTOK;

    __shared__ float in_t[18][256];
    __shared__ float kr_t[64][64];
    __shared__ float v_t[64][64];
    __shared__ float wq[2][9];
    __shared__ float bq[2];
    __shared__ float red[256];

    if (t < 18) ((float*)wq)[t] = qkw[2 * ch * 9 + t];
    if (t < 2)  bq[t] = qkb[2 * ch + t];

    const int ck = t & 63;          // conv-phase: k channel
    const int g  = t >> 6;          // conv-phase: row group; kv-phase: head
    const int d0 = ((t & 63) >> 3) << 1;
    const int e0 = (t & 7) << 1;
    const int h  = g;

    float km_acc = 0.f;
    float a00 = 0.f, a01 = 0.f, a10 = 0.f, a11 = 0.f;

    for (int y0 = 0; y0 < 256; y0 += 16) {
        // stage input rows y0-1 .. y0+16
        for (int j = t; j < 18 * 64; j += 256) {
            int row = j >> 6, c4 = (j & 63) << 2;
            int y = y0 - 1 + row;
            float4 val = make_float4(0.f, 0.f, 0.f, 0.f);
            if (y >= 0 && y < 256)
                val = *(const float4*)(xplane + y * 256 + c4);
            *(float4*)(&in_t[row][c4]) = val;
        }
        // stage v tile: 64 tokens x 64 channels (contiguous 256B per token)
        for (int j = t; j < 64 * 16; j += 256) {
            int tok = j >> 4, f4 = (j & 15) << 2;
            int n = (2 * ch + (tok >> 5)) * 512 + 2 * y0 + (tok & 31);
            *(float4*)(&v_t[tok][f4]) = *(const float4*)(xb + (size_t)n * 64 + f4);
        }
        __syncthreads();

        // conv (k columns only) + elu+1 + rope -> kr_t
        #pragma unroll
        for (int co2 = 0; co2 < 2; ++co2)
        #pragma unroll
        for (int xb2 = 0; xb2 < 2; ++xb2)
        #pragma unroll
        for (int yi = 0; yi < 4; ++yi) {
            int yl = g + 4 * yi;
            int xx = xb2 * 128 + 64 + ck;
            float acc = bq[co2];
            #pragma unroll
            for (int ky = 0; ky < 3; ++ky)
            #pragma unroll
            for (int kx = 0; kx < 3; ++kx) {
                int xc = xx + kx - 1;
                float iv = (xc >= 0 && xc < 256) ? in_t[yl + ky][xc] : 0.f;
                acc = fmaf(wq[co2][ky * 3 + kx], iv, acc);
            }
            float kh = acc > 0.f ? acc + 1.f : expf(acc);
            km_acc += kh;
            int w_i = (2 * (y0 + yl) + xb2) & 255;
            float2 cs = *(const float2*)(ws + CS_OFF + (((w_i << 5) + (ck >> 1)) << 1));
            float partner = __shfl_xor(kh, 1);
            float kr = (ck & 1) ? fmaf(partner, cs.y, kh * cs.x)
                                : fmaf(-partner, cs.y, kh * cs.x);
            kr_t[co2 * 32 + yl * 2 + xb2][ck] = kr;
        }
        __syncthreads();

        // kv accumulate: wave = head, 2x2 (d,e) tile per lane
        #pragma unroll 8
        for (int tok = 0; tok < 64; ++tok) {
            float2 kk = *(const float2*)(&kr_t[tok][(h << 4) + d0]);
            float2 vv = *(const float2*)(&v_t[tok][(h << 4) + e0]);
            a00 = fmaf(kk.x, vv.x, a00);
            a01 = fmaf(kk.x, vv.y, a01);
            a10 = fmaf(kk.y, vv.x, a10);
            a11 = fmaf(kk.y, vv.y, a11);
        }
        __syncthreads();
    }

    float* kvg = ws + KV_OFF + ((b * 4 + h) * 16) * 16;
    atomicAdd(&kvg[(d0    ) * 16 + e0    ], a00);
    atomicAdd(&kvg[(d0    ) * 16 + e0 + 1], a01);
    atomicAdd(&kvg[(d0 + 1) * 16 + e0    ], a10);
    atomicAdd(&kvg[(d0 + 1) * 16 + e0 + 1], a11);

    red[t] = km_acc;
    __syncthreads();
    if (t < 64) {
        float s = red[t] + red[t + 64] + red[t + 128] + red[t + 192];
        atomicAdd(ws + KM_OFF + b * 64 + t, s);
    }
}

// K3: per (b, ch): conv q-columns + elu + rope + attention + fused lepe + write
__global__ __launch_bounds__(256) void k3_out(const float* __restrict__ x,
        const float* __restrict__ qkw, const float* __restrict__ qkb,
        const float* __restrict__ lw, const float* __restrict__ lb,
        const float* __restrict__ ws, float* __restrict__ out) {
    const int b  = blockIdx.x >> 6;
    const int ch = blockIdx.x & 63;
    const int t  = threadIdx.x;
    const float* xb     = x + (size_t)b * (NC * NTOK);
    const float* xplane = xb + ch * NTOK;
    float* outb = out + (size_t)b * (NC * NTOK);

    __shared__ float in_t[18][256];
    __shared__ float q_t[64][65];
    __shared__ float o_t[64][65];
    __shared__ float wq[2][9];
    __shared__ float bq[2];
    __shared__ float lw_s[64][9];
    __shared__ float lb_s[64];

    if (t < 18) ((float*)wq)[t] = qkw[2 * ch * 9 + t];
    if (t < 2)  bq[t] = qkb[2 * ch + t];
    for (int j = t; j < 64 * 9; j += 256) ((float*)lw_s)[j] = lw[j];
    if (t < 64) lb_s[t] = lb[t];

    const int cq  = t & 63;
    const int g   = t >> 6;
    const int tok = t & 63;
    const int hu  = __builtin_amdgcn_readfirstlane(t >> 6);  // wave = head

    const float* kv_h = ws + KV_OFF + (b * 4 + hu) * 256;
    const float* km_h = ws + KM_OFF + b * 64 + hu * 16;
    const float inv_n = 1.0f / 65536.0f;

    for (int y0 = 0; y0 < 256; y0 += 16) {
        for (int j = t; j < 18 * 64; j += 256) {
            int row = j >> 6, c4 = (j & 63) << 2;
            int y = y0 - 1 + row;
            float4 val = make_float4(0.f, 0.f, 0.f, 0.f);
            if (y >= 0 && y < 256)
                val = *(const float4*)(xplane + y * 256 + c4);
            *(float4*)(&in_t[row][c4]) = val;
        }
        __syncthreads();

        // conv (q columns only) + elu+1 -> q_t
        #pragma unroll
        for (int co2 = 0; co2 < 2; ++co2)
        #pragma unroll
        for (int xb2 = 0; xb2 < 2; ++xb2)
        #pragma unroll
        for (int yi = 0; yi < 4; ++yi) {
            int yl = g + 4 * yi;
            int xx = xb2 * 128 + cq;
            float acc = bq[co2];
            #pragma unroll
            for (int ky = 0; ky < 3; ++ky)
            #pragma unroll
            for (int kx = 0; kx < 3; ++kx) {
                int xc = xx + kx - 1;
                float iv = (xc >= 0 && xc < 256) ? in_t[yl + ky][xc] : 0.f;
                acc = fmaf(wq[co2][ky * 3 + kx], iv, acc);
            }
            q_t[co2 * 32 + yl * 2 + xb2][cq] = acc > 0.f ? acc + 1.f : expf(acc);
        }
        __syncthreads();

        // attention + lepe for (token = lane, head = wave)
        {
            int co2 = tok >> 5;
            int r   = 2 * y0 + (tok & 31);       // 2y+xb in [0,512)
            int w_i = r & 255;                   // rope angle index == image X
            int Yim = (2 * ch + co2) * 2 + (r >> 8);

            float qv[16], qr[16];
            #pragma unroll
            for (int d = 0; d < 16; ++d) qv[d] = q_t[tok][hu * 16 + d];

            float zd = 0.f;
            #pragma unroll
            for (int d = 0; d < 16; ++d) zd = fmaf(qv[d], km_h[d], zd);
            float zinv = 1.0f / (zd * inv_n + 1e-6f);

            const float2* csp = (const float2*)(ws + CS_OFF) + (w_i << 5) + hu * 8;
            #pragma unroll
            for (int p = 0; p < 8; ++p) {
                float2 cs = csp[p];
                qr[2 * p]     = qv[2 * p] * cs.x - qv[2 * p + 1] * cs.y;
                qr[2 * p + 1] = qv[2 * p] * cs.y + qv[2 * p + 1] * cs.x;
            }

            float oa[16];
            #pragma unroll
            for (int e = 0; e < 16; ++e) oa[e] = 0.f;
            #pragma unroll
            for (int d = 0; d < 16; ++d) {
                float qd = qr[d];
                const float* kvr = kv_h + d * 16;   // uniform -> s_load
                #pragma unroll
                for (int e = 0; e < 16; ++e) oa[e] = fmaf(qd, kvr[e], oa[e]);
            }
            float zs = zinv * inv_n;

            float lp[16];
            #pragma unroll
            for (int e = 0; e < 16; ++e) lp[e] = lb_s[hu * 16 + e];
            #pragma unroll
            for (int dy = -1; dy <= 1; ++dy) {
                int Y2 = Yim + dy;
                if (Y2 < 0 || Y2 > 255) continue;
                #pragma unroll
                for (int dx = -1; dx <= 1; ++dx) {
                    int X2 = w_i + dx;
                    if (X2 < 0 || X2 > 255) continue;
                    const float* src = xb + ((size_t)(Y2 * 256 + X2)) * 64 + hu * 16;
                    float sv[16];
                    *(float4*)(&sv[0])  = *(const float4*)(src);
                    *(float4*)(&sv[4])  = *(const float4*)(src + 4);
                    *(float4*)(&sv[8])  = *(const float4*)(src + 8);
                    *(float4*)(&sv[12]) = *(const float4*)(src + 12);
                    int kt = (dy + 1) * 3 + (dx + 1);
                    #pragma unroll
                    for (int e = 0; e < 16; ++e)
                        lp[e] = fmaf(lw_s[hu * 16 + e][kt], sv[e], lp[e]);
                }
            }
            #pragma unroll
            for (int e = 0; e < 16; ++e)
                o_t[tok][hu * 16 + e] = fmaf(oa[e], zs, lp[e]);
        }
        __syncthreads();

        // coalesced write: out[b][c][n], 32 consecutive n per half-wave
        {
            int co2w = tok >> 5;
            size_t base = (size_t)((2 * ch + co2w) * 512 + 2 * y0 + (tok & 31));
            #pragma unroll
            for (int kk = 0; kk < 16; ++kk) {
                int c = g + 4 * kk;
                outb[(size_t)c * NTOK + base] = o_t[tok][c];
            }
        }
        __syncthreads();
    }
}

extern "C" void kernel_launch(void* const* d_in, const int* in_sizes, int n_in,
                              void* d_out, int out_size, void* d_ws, size_t ws_size,
                              hipStream_t stream) {
    const float* x   = (const float*)d_in[0];
    const float* qkw = (const float*)d_in[1];
    const float* qkb = (const float*)d_in[2];
    const float* lw  = (const float*)d_in[3];
    const float* lb  = (const float*)d_in[4];
    float* out = (float*)d_out;
    float* ws  = (float*)d_ws;

    hipLaunchKernelGGL(k0_setup, dim3(32),  dim3(256), 0, stream, ws);
    hipLaunchKernelGGL(k1_kv,    dim3(512), dim3(256), 0, stream, x, qkw, qkb, ws);
    hipLaunchKernelGGL(k3_out,   dim3(512), dim3(256), 0, stream, x, qkw, qkb, lw, lb, ws, out);
}

// Round 2
// 535.849 us; speedup vs baseline: 1.0691x; 1.0691x over previous
//
#include <hip/hip_runtime.h>
#include <math.h>

#define NC 64
#define NTOK 65536

// workspace layout (floats)
constexpr int CS_OFF = 0;        // float2 [256][32]  -> 16384 floats
constexpr int KV_OFF = 16384;    // [8][4][16][16]    -> 8192 floats
constexpr int KM_OFF = 24576;    // [8][64]           -> 512 floats

__global__ __launch_bounds__(256) void k0_setup(float* __restrict__ ws) {
    int i = blockIdx.x * 256 + threadIdx.x;
    if (i < 8192) {
        int w = i >> 5, p = i & 31;
        double th = pow(10000.0, -(double)p / 32.0);
        double ang = (double)w * th;
        ws[CS_OFF + 2 * i]     = (float)cos(ang);
        ws[CS_OFF + 2 * i + 1] = (float)sin(ang);
        ws[KV_OFF + i] = 0.0f;
        if (i < 512) ws[KM_OFF + i] = 0.0f;
    }
}

// K1: per (b, ch, ychunk): conv k-columns + elu + rope, accumulate kv & k_mean.
// 8-row strips; stages only image cols [60,131] U [188,255] (what k-conv needs).
__global__ __launch_bounds__(256) void k1_kv(const float* __restrict__ x,
        const float* __restrict__ qkw, const float* __restrict__ qkb,
        float* __restrict__ ws) {
    const int idx = blockIdx.x;
    const int b   = idx >> 8;
    const int ch  = (idx & 255) >> 2;
    const int ybase = (idx & 3) * 64;
    const int t  = threadIdx.x;
    const float* xb     = x + (size_t)b * (NC * NTOK);
    const float* xplane = xb + ch * NTOK;

    __shared__ float in_t[10][140];
    __shared__ float kr_t[32][64];
    __shared__ float v_t[32][64];
    __shared__ float wq[2][9];
    __shared__ float bq[2];

    if (t < 18) ((float*)wq)[t] = qkw[2 * ch * 9 + t];
    if (t < 2)  bq[t] = qkb[2 * ch + t];

    const int ck = t & 63;
    const int g  = t >> 6;
    const int d0 = ((t & 63) >> 3) << 1;
    const int e0 = (t & 7) << 1;
    const int h  = g;

    float km_acc = 0.f;
    float a00 = 0.f, a01 = 0.f, a10 = 0.f, a11 = 0.f;

    for (int y0 = ybase; y0 < ybase + 64; y0 += 8) {
        // stage rows y0-1..y0+8, cols A [60..131]->pos[0..71], B [188..255]->pos[72..139]
        for (int j = t; j < 10 * 35; j += 256) {
            int row = j / 35, s = j - row * 35;
            int y = y0 - 1 + row;
            int gcol, pos;
            if (s < 18) { gcol = 60 + 4 * s;        pos = 4 * s; }
            else        { gcol = 188 + 4 * (s - 18); pos = 72 + 4 * (s - 18); }
            float4 val = make_float4(0.f, 0.f, 0.f, 0.f);
            if (y >= 0 && y < 256)
                val = *(const float4*)(xplane + y * 256 + gcol);
            *(float4*)(&in_t[row][pos]) = val;
        }
        // stage v tile: 32 tokens x 64 ch
        for (int j = t; j < 32 * 16; j += 256) {
            int tok = j >> 4, f4 = (j & 15) << 2;
            int n = (2 * ch + (tok >> 4)) * 512 + 2 * y0 + (tok & 15);
            *(float4*)(&v_t[tok][f4]) = *(const float4*)(xb + (size_t)n * 64 + f4);
        }
        __syncthreads();

        // conv (k columns) + elu+1 + rope -> kr_t
        #pragma unroll
        for (int co2 = 0; co2 < 2; ++co2)
        #pragma unroll
        for (int xb2 = 0; xb2 < 2; ++xb2)
        #pragma unroll
        for (int yi = 0; yi < 2; ++yi) {
            int yl = g + 4 * yi;
            float acc = bq[co2];
            #pragma unroll
            for (int ky = 0; ky < 3; ++ky)
            #pragma unroll
            for (int kx = 0; kx < 3; ++kx) {
                int xc = (xb2 ? 192 : 64) + ck + kx - 1;
                int pos = xb2 ? xc - 116 : xc - 60;
                float iv = (xb2 && xc >= 256) ? 0.f : in_t[yl + ky][pos];
                acc = fmaf(wq[co2][ky * 3 + kx], iv, acc);
            }
            float kh = acc > 0.f ? acc + 1.f : expf(acc);
            km_acc += kh;
            int w_i = (2 * (y0 + yl) + xb2) & 255;
            float2 cs = *(const float2*)(ws + CS_OFF + (((w_i << 5) + (ck >> 1)) << 1));
            float partner = __shfl_xor(kh, 1);
            float kr = (ck & 1) ? fmaf(partner, cs.y, kh * cs.x)
                                : fmaf(-partner, cs.y, kh * cs.x);
            kr_t[co2 * 16 + yl * 2 + xb2][ck] = kr;
        }
        __syncthreads();

        // kv accumulate: wave = head, 2x2 (d,e) tile per lane
        #pragma unroll 8
        for (int tok = 0; tok < 32; ++tok) {
            float2 kk = *(const float2*)(&kr_t[tok][(h << 4) + d0]);
            float2 vv = *(const float2*)(&v_t[tok][(h << 4) + e0]);
            a00 = fmaf(kk.x, vv.x, a00);
            a01 = fmaf(kk.x, vv.y, a01);
            a10 = fmaf(kk.y, vv.x, a10);
            a11 = fmaf(kk.y, vv.y, a11);
        }
        __syncthreads();
    }

    float* kvg = ws + KV_OFF + ((b * 4 + h) * 16) * 16;
    atomicAdd(&kvg[(d0    ) * 16 + e0    ], a00);
    atomicAdd(&kvg[(d0    ) * 16 + e0 + 1], a01);
    atomicAdd(&kvg[(d0 + 1) * 16 + e0    ], a10);
    atomicAdd(&kvg[(d0 + 1) * 16 + e0 + 1], a11);

    // k_mean reduce (alias onto v_t, which is dead now)
    float* red = &v_t[0][0];
    red[t] = km_acc;
    __syncthreads();
    if (t < 64) {
        float s = red[t] + red[t + 64] + red[t + 128] + red[t + 192];
        atomicAdd(ws + KM_OFF + b * 64 + t, s);
    }
}

// K3: per (b, ch, ychunk): conv q-columns + elu + rope + attention + lepe + write
__global__ __launch_bounds__(256) void k3_out(const float* __restrict__ x,
        const float* __restrict__ qkw, const float* __restrict__ qkb,
        const float* __restrict__ lw, const float* __restrict__ lb,
        const float* __restrict__ ws, float* __restrict__ out) {
    const int idx = blockIdx.x;
    const int b   = idx >> 8;
    const int ch  = (idx & 255) >> 2;
    const int ybase = (idx & 3) * 64;
    const int t  = threadIdx.x;
    const float* xb     = x + (size_t)b * (NC * NTOK);
    const float* xplane = xb + ch * NTOK;
    float* outb = out + (size_t)b * (NC * NTOK);

    __shared__ union SU {
        float in_t[18][140];   // staged conv input (q cols)
        float o_t[64][65];     // output transpose tile (disjoint lifetime)
    } u;
    __shared__ float q_t[64][65];
    __shared__ float wq[2][9];
    __shared__ float bq[2];
    __shared__ float lw_s[64][9];
    __shared__ float lb_s[64];

    if (t < 18) ((float*)wq)[t] = qkw[2 * ch * 9 + t];
    if (t < 2)  bq[t] = qkb[2 * ch + t];
    for (int j = t; j < 64 * 9; j += 256) ((float*)lw_s)[j] = lw[j];
    if (t < 64) lb_s[t] = lb[t];

    const int cq  = t & 63;
    const int g   = t >> 6;
    const int tok = t & 63;
    const int hu  = __builtin_amdgcn_readfirstlane(t >> 6);  // wave = head

    const float* kv_h = ws + KV_OFF + (b * 4 + hu) * 256;
    const float* km_h = ws + KM_OFF + b * 64 + hu * 16;
    const float inv_n = 1.0f / 65536.0f;

    for (int y0 = ybase; y0 < ybase + 64; y0 += 16) {
        // stage rows y0-1..y0+16, cols A [0..67]->pos[0..67], B [124..195]->pos[68..139]
        for (int j = t; j < 18 * 35; j += 256) {
            int row = j / 35, s = j - row * 35;
            int y = y0 - 1 + row;
            int gcol, pos;
            if (s < 17) { gcol = 4 * s;              pos = 4 * s; }
            else        { gcol = 124 + 4 * (s - 17); pos = 68 + 4 * (s - 17); }
            float4 val = make_float4(0.f, 0.f, 0.f, 0.f);
            if (y >= 0 && y < 256)
                val = *(const float4*)(xplane + y * 256 + gcol);
            *(float4*)(&u.in_t[row][pos]) = val;
        }
        __syncthreads();

        // conv (q columns) + elu+1 -> q_t
        #pragma unroll
        for (int co2 = 0; co2 < 2; ++co2)
        #pragma unroll
        for (int xb2 = 0; xb2 < 2; ++xb2)
        #pragma unroll
        for (int yi = 0; yi < 4; ++yi) {
            int yl = g + 4 * yi;
            float acc = bq[co2];
            #pragma unroll
            for (int ky = 0; ky < 3; ++ky)
            #pragma unroll
            for (int kx = 0; kx < 3; ++kx) {
                int xc = (xb2 ? 128 : 0) + cq + kx - 1;
                int pos = xb2 ? xc - 56 : xc;
                float iv = (!xb2 && xc < 0) ? 0.f : u.in_t[yl + ky][pos];
                acc = fmaf(wq[co2][ky * 3 + kx], iv, acc);
            }
            q_t[co2 * 32 + yl * 2 + xb2][cq] = acc > 0.f ? acc + 1.f : expf(acc);
        }
        __syncthreads();

        // attention + lepe for (token = lane, head = wave) -> u.o_t
        {
            int co2 = tok >> 5;
            int r   = 2 * y0 + (tok & 31);       // token index within plane [0,512)
            int w_i = r & 255;                   // rope angle index == image X
            int Yim = (2 * ch + co2) * 2 + (r >> 8);

            float qv[16], qr[16];
            #pragma unroll
            for (int d = 0; d < 16; ++d) qv[d] = q_t[tok][hu * 16 + d];

            float zd = 0.f;
            #pragma unroll
            for (int d = 0; d < 16; ++d) zd = fmaf(qv[d], km_h[d], zd);
            float zinv = 1.0f / (zd * inv_n + 1e-6f);

            const float2* csp = (const float2*)(ws + CS_OFF) + (w_i << 5) + hu * 8;
            #pragma unroll
            for (int p = 0; p < 8; ++p) {
                float2 cs = csp[p];
                qr[2 * p]     = qv[2 * p] * cs.x - qv[2 * p + 1] * cs.y;
                qr[2 * p + 1] = qv[2 * p] * cs.y + qv[2 * p + 1] * cs.x;
            }

            float oa[16];
            #pragma unroll
            for (int e = 0; e < 16; ++e) oa[e] = 0.f;
            #pragma unroll
            for (int d = 0; d < 16; ++d) {
                float qd = qr[d];
                const float* kvr = kv_h + d * 16;   // uniform -> s_load
                #pragma unroll
                for (int e = 0; e < 16; ++e) oa[e] = fmaf(qd, kvr[e], oa[e]);
            }
            float zs = zinv * inv_n;

            float lp[16];
            #pragma unroll
            for (int e = 0; e < 16; ++e) lp[e] = lb_s[hu * 16 + e];
            #pragma unroll
            for (int dy = -1; dy <= 1; ++dy) {
                int Y2 = Yim + dy;
                if (Y2 < 0 || Y2 > 255) continue;
                #pragma unroll
                for (int dx = -1; dx <= 1; ++dx) {
                    int X2 = w_i + dx;
                    if (X2 < 0 || X2 > 255) continue;
                    const float* src = xb + ((size_t)(Y2 * 256 + X2)) * 64 + hu * 16;
                    float sv[16];
                    *(float4*)(&sv[0])  = *(const float4*)(src);
                    *(float4*)(&sv[4])  = *(const float4*)(src + 4);
                    *(float4*)(&sv[8])  = *(const float4*)(src + 8);
                    *(float4*)(&sv[12]) = *(const float4*)(src + 12);
                    int kt = (dy + 1) * 3 + (dx + 1);
                    #pragma unroll
                    for (int e = 0; e < 16; ++e)
                        lp[e] = fmaf(lw_s[hu * 16 + e][kt], sv[e], lp[e]);
                }
            }
            #pragma unroll
            for (int e = 0; e < 16; ++e)
                u.o_t[tok][hu * 16 + e] = fmaf(oa[e], zs, lp[e]);
        }
        __syncthreads();

        // coalesced write: out[b][c][n]
        {
            int co2w = tok >> 5;
            size_t base = (size_t)((2 * ch + co2w) * 512 + 2 * y0 + (tok & 31));
            #pragma unroll
            for (int kk = 0; kk < 16; ++kk) {
                int c = g + 4 * kk;
                outb[(size_t)c * NTOK + base] = u.o_t[tok][c];
            }
        }
        __syncthreads();
    }
}

extern "C" void kernel_launch(void* const* d_in, const int* in_sizes, int n_in,
                              void* d_out, int out_size, void* d_ws, size_t ws_size,
                              hipStream_t stream) {
    const float* x   = (const float*)d_in[0];
    const float* qkw = (const float*)d_in[1];
    const float* qkb = (const float*)d_in[2];
    const float* lw  = (const float*)d_in[3];
    const float* lb  = (const float*)d_in[4];
    float* out = (float*)d_out;
    float* ws  = (float*)d_ws;

    hipLaunchKernelGGL(k0_setup, dim3(32),   dim3(256), 0, stream, ws);
    hipLaunchKernelGGL(k1_kv,    dim3(2048), dim3(256), 0, stream, x, qkw, qkb, ws);
    hipLaunchKernelGGL(k3_out,   dim3(2048), dim3(256), 0, stream, x, qkw, qkb, lw, lb, ws, out);
}